// Round 4
// baseline (491.896 us; speedup 1.0000x reference)
//
#include <hip/hip_runtime.h>

#define IN_DIM  128
#define HIDDEN  512
#define NCLASS  10
#define TSTEPS  512
#define BATCH   512
#define BETA    0.9f
#define THRESH  0.15f

typedef __attribute__((ext_vector_type(8))) short bf16x8;
typedef __attribute__((ext_vector_type(4))) float f32x4;

__device__ __forceinline__ unsigned short f2bf_rne(float f) {
    unsigned int u = __float_as_uint(f);
    u += 0x7FFFu + ((u >> 16) & 1u);
    return (unsigned short)(u >> 16);
}
__device__ __forceinline__ float bf2f(unsigned short h) {
    return __uint_as_float(((unsigned int)h) << 16);
}

// 8 f32 (scaled by s) -> hi bf16x8 + residual-lo bf16x8 (fp32-accurate split)
__device__ __forceinline__ void cvt8s(const float4 a, const float4 b, float s,
                                      bf16x8* hi, bf16x8* lo) {
    float v[8] = {a.x * s, a.y * s, a.z * s, a.w * s,
                  b.x * s, b.y * s, b.z * s, b.w * s};
#pragma unroll
    for (int e = 0; e < 8; ++e) {
        unsigned short h = f2bf_rne(v[e]);
        (*hi)[e] = (short)h;
        (*lo)[e] = (short)f2bf_rne(v[e] - bf2f(h));
    }
}

// ---------- Pass 1: x fp32 -> (2x) bf16 hi + residual lo, done ONCE ----------
__global__ __launch_bounds__(256, 4) void conv_x(
    const float* __restrict__ x, unsigned short* __restrict__ xh,
    unsigned short* __restrict__ xl)
{
    size_t i = ((size_t)blockIdx.x * 256 + threadIdx.x) * 8;
    const float4* p = reinterpret_cast<const float4*>(x + i);
    float4 a = p[0], b = p[1];
    bf16x8 h, l;
    cvt8s(a, b, 2.0f, &h, &l);
    *(bf16x8*)(xh + i) = h;
    *(bf16x8*)(xl + i) = l;
}

// ---------- Pass 2: fused SNN, no LDS, no barriers ----------
// Block = 16 batch rows x 64 hidden (4 waves, wave = 16x16 tile).
// A-frags loaded straight from global (bf16 pre-converted) with a 4-deep
// rotating register prefetch; W1 hi/lo fragments pinned in VGPRs.
__global__ __launch_bounds__(256, 1) void snn_mfma_g(
    const unsigned short* __restrict__ xh,  // [B, T, 128] bf16 of 2x
    const unsigned short* __restrict__ xl,  // residual
    const float* __restrict__ W1,           // [H, 128]
    const float* __restrict__ b1,           // [H]
    float* __restrict__ cnt_ws)             // [B, H]
{
    const int bid  = blockIdx.x;
    const int hblk = bid >> 5;     // 0..7; bid%8==bblk%8 -> x-sharing blocks co-XCD
    const int bblk = bid & 31;     // 0..31
    const int b0   = bblk * 16;
    const int tid  = threadIdx.x;
    const int wave = tid >> 6;
    const int lane = tid & 63;
    const int l15  = lane & 15;
    const int lg   = lane >> 4;
    const int hbase = hblk * 64 + wave * 16;

    // B-operand fragments from W1 (fp32->hi/lo, once; held all T steps)
    bf16x8 whi[4], wlo[4];
    {
        const float* wp = W1 + (size_t)(hbase + l15) * IN_DIM + lg * 8;
#pragma unroll
        for (int kf = 0; kf < 4; ++kf) {
            const float4* p = reinterpret_cast<const float4*>(wp + kf * 32);
            cvt8s(p[0], p[1], 1.0f, &whi[kf], &wlo[kf]);
        }
    }
    const float b1h = b1[hbase + l15];

    // per-lane byte base: row (b0+l15), k-chunk lg
    const char* pxh = (const char*)(xh + ((size_t)(b0 + l15) * TSTEPS) * IN_DIM + lg * 8);
    const char* pxl = (const char*)(xl + ((size_t)(b0 + l15) * TSTEPS) * IN_DIM + lg * 8);

    f32x4 mem = {0.f, 0.f, 0.f, 0.f};
    f32x4 cnt = {0.f, 0.f, 0.f, 0.f};

    bf16x8 lxh[4][4], lxl[4][4];   // [slot][kf], static-indexed only
    // prologue: fill slots with t = 0..3
#pragma unroll
    for (int j = 0; j < 4; ++j)
#pragma unroll
        for (int kf = 0; kf < 4; ++kf) {
            lxh[j][kf] = *(const bf16x8*)(pxh + j * 256 + kf * 64);
            lxl[j][kf] = *(const bf16x8*)(pxl + j * 256 + kf * 64);
        }

#define TSTEP(J, PFJ)                                                          \
    {                                                                          \
        f32x4 chh = {b1h, b1h, b1h, b1h};                                      \
        f32x4 chl = {0.f, 0.f, 0.f, 0.f};                                      \
        f32x4 clh = {0.f, 0.f, 0.f, 0.f};                                      \
        _Pragma("unroll")                                                      \
        for (int kf = 0; kf < 4; ++kf) {                                       \
            chh = __builtin_amdgcn_mfma_f32_16x16x32_bf16(lxh[(J) & 3][kf], whi[kf], chh, 0, 0, 0); \
            chl = __builtin_amdgcn_mfma_f32_16x16x32_bf16(lxh[(J) & 3][kf], wlo[kf], chl, 0, 0, 0); \
            clh = __builtin_amdgcn_mfma_f32_16x16x32_bf16(lxl[(J) & 3][kf], whi[kf], clh, 0, 0, 0); \
        }                                                                      \
        _Pragma("unroll")                                                      \
        for (int kf = 0; kf < 4; ++kf) {                                       \
            lxh[(J) & 3][kf] = *(const bf16x8*)(pxh + (PFJ) * 256 + kf * 64);  \
            lxl[(J) & 3][kf] = *(const bf16x8*)(pxl + (PFJ) * 256 + kf * 64);  \
        }                                                                      \
        _Pragma("unroll")                                                      \
        for (int r = 0; r < 4; ++r) {                                          \
            float cur = (chh[r] + chl[r]) + clh[r];                            \
            float dec = fmaf(BETA, mem[r], cur);                               \
            mem[r] = (mem[r] > THRESH) ? (dec - THRESH) : dec;                 \
            cnt[r] += (mem[r] > THRESH) ? 1.0f : 0.0f;                         \
        }                                                                      \
    }

    for (int w = 0; w < 63; ++w) {
#pragma unroll
        for (int j = 0; j < 8; ++j)
            TSTEP(j, j + 4)
        pxh += 8 * 256;
        pxl += 8 * 256;
    }
    // final window: prefetch clamped to t=511 (no OOB, results unused)
#pragma unroll
    for (int j = 0; j < 8; ++j)
        TSTEP(j, 7)
#undef TSTEP

    // store spike counts; C-layout row = lg*4+r, col = l15
    float* cp = cnt_ws + (size_t)b0 * HIDDEN + hbase + l15;
#pragma unroll
    for (int r = 0; r < 4; ++r)
        cp[(size_t)(lg * 4 + r) * HIDDEN] = cnt[r];
}

// ---------- Fallback (R2 path) if ws too small: fused LDS version ----------
__global__ __launch_bounds__(256, 1) void snn_mfma_lds(
    const float* __restrict__ x, const float* __restrict__ W1,
    const float* __restrict__ b1, float* __restrict__ cnt_ws)
{
    __shared__ short ldsA[2][2][16 * IN_DIM];
    const int bid  = blockIdx.x;
    const int hblk = bid >> 5;
    const int bblk = bid & 31;
    const int b0   = bblk * 16;
    const int tid  = threadIdx.x;
    const int wave = tid >> 6;
    const int lane = tid & 63;
    const int l15  = lane & 15;
    const int lg   = lane >> 4;
    const int hbase = hblk * 64 + wave * 16;

    bf16x8 whi[4], wlo[4];
    {
        const float* wp = W1 + (size_t)(hbase + l15) * IN_DIM + lg * 8;
#pragma unroll
        for (int kf = 0; kf < 4; ++kf) {
            const float4* p = reinterpret_cast<const float4*>(wp + kf * 32);
            cvt8s(p[0], p[1], 1.0f, &whi[kf], &wlo[kf]);
        }
    }
    const float b1h = b1[hbase + l15];
    const int m_w  = wave * 4 + lg;
    const int widx = m_w * IN_DIM + ((l15 ^ (m_w & 7)) * 8);
    const float* xrow = x + ((size_t)(b0 + m_w) * TSTEPS) * IN_DIM + l15 * 8;
    int ridx[4];
#pragma unroll
    for (int kf = 0; kf < 4; ++kf)
        ridx[kf] = l15 * IN_DIM + (((lg + 4 * kf) ^ (l15 & 7)) * 8);

    f32x4 mem = {0.f, 0.f, 0.f, 0.f};
    f32x4 cnt = {0.f, 0.f, 0.f, 0.f};
    {
        const float4* p = reinterpret_cast<const float4*>(xrow);
        bf16x8 h8, l8;
        cvt8s(p[0], p[1], 2.0f, &h8, &l8);
        *(bf16x8*)&ldsA[0][0][widx] = h8;
        *(bf16x8*)&ldsA[0][1][widx] = l8;
    }
    float4 rA0, rA1, rB0, rB1;
    {
        const float4* p1 = reinterpret_cast<const float4*>(xrow + 1 * IN_DIM);
        rA0 = p1[0]; rA1 = p1[1];
        const float4* p2 = reinterpret_cast<const float4*>(xrow + 2 * IN_DIM);
        rB0 = p2[0]; rB1 = p2[1];
    }
    __syncthreads();

#define SNN_BODY(T_CUR, RC0, RC1)                                              \
    {                                                                          \
        const int buf = (T_CUR) & 1;                                           \
        if ((T_CUR) + 1 < TSTEPS) {                                            \
            bf16x8 h8, l8;                                                     \
            cvt8s(RC0, RC1, 2.0f, &h8, &l8);                                   \
            *(bf16x8*)&ldsA[buf ^ 1][0][widx] = h8;                            \
            *(bf16x8*)&ldsA[buf ^ 1][1][widx] = l8;                            \
        }                                                                      \
        bf16x8 ahi[4], alo[4];                                                 \
        _Pragma("unroll")                                                      \
        for (int kf = 0; kf < 4; ++kf) {                                       \
            ahi[kf] = *(const bf16x8*)&ldsA[buf][0][ridx[kf]];                 \
            alo[kf] = *(const bf16x8*)&ldsA[buf][1][ridx[kf]];                 \
        }                                                                      \
        {                                                                      \
            int tld = (T_CUR) + 3;                                             \
            if (tld > TSTEPS - 1) tld = TSTEPS - 1;                            \
            const float4* p = reinterpret_cast<const float4*>(                 \
                xrow + (size_t)tld * IN_DIM);                                  \
            RC0 = p[0]; RC1 = p[1];                                            \
        }                                                                      \
        f32x4 chh = {b1h, b1h, b1h, b1h};                                      \
        f32x4 chl = {0.f, 0.f, 0.f, 0.f};                                      \
        f32x4 clh = {0.f, 0.f, 0.f, 0.f};                                      \
        _Pragma("unroll")                                                      \
        for (int kf = 0; kf < 4; ++kf) {                                       \
            chh = __builtin_amdgcn_mfma_f32_16x16x32_bf16(ahi[kf], whi[kf], chh, 0, 0, 0); \
            chl = __builtin_amdgcn_mfma_f32_16x16x32_bf16(ahi[kf], wlo[kf], chl, 0, 0, 0); \
            clh = __builtin_amdgcn_mfma_f32_16x16x32_bf16(alo[kf], whi[kf], clh, 0, 0, 0); \
        }                                                                      \
        _Pragma("unroll")                                                      \
        for (int r = 0; r < 4; ++r) {                                          \
            float cur = (chh[r] + chl[r]) + clh[r];                            \
            float dec = fmaf(BETA, mem[r], cur);                               \
            mem[r] = (mem[r] > THRESH) ? (dec - THRESH) : dec;                 \
            cnt[r] += (mem[r] > THRESH) ? 1.0f : 0.0f;                         \
        }                                                                      \
        __syncthreads();                                                       \
    }

    for (int t = 0; t < TSTEPS; t += 2) {
        SNN_BODY(t,     rA0, rA1)
        SNN_BODY(t + 1, rB0, rB1)
    }
#undef SNN_BODY

    float* cp = cnt_ws + (size_t)b0 * HIDDEN + hbase + l15;
#pragma unroll
    for (int r = 0; r < 4; ++r)
        cp[(size_t)(lg * 4 + r) * HIDDEN] = cnt[r];
}

// out[b,c] = (sum_h cnt[b,h] * W2[c,h]) / T + b2[c]
__global__ __launch_bounds__(64, 1) void snn_out(
    const float* __restrict__ cnt_ws, const float* __restrict__ W2,
    const float* __restrict__ b2, float* __restrict__ out)
{
    const int b = blockIdx.x;
    const int lane = threadIdx.x;
    float c8[8];
#pragma unroll
    for (int j = 0; j < 8; ++j)
        c8[j] = cnt_ws[(size_t)b * HIDDEN + lane + 64 * j];
#pragma unroll
    for (int c = 0; c < NCLASS; ++c) {
        float s = 0.f;
#pragma unroll
        for (int j = 0; j < 8; ++j)
            s = fmaf(c8[j], W2[c * HIDDEN + lane + 64 * j], s);
#pragma unroll
        for (int off = 32; off >= 1; off >>= 1)
            s += __shfl_xor(s, off, 64);
        if (lane == c)
            out[(size_t)b * NCLASS + c] = s * (1.0f / (float)TSTEPS) + b2[c];
    }
}

extern "C" void kernel_launch(void* const* d_in, const int* in_sizes, int n_in,
                              void* d_out, int out_size, void* d_ws, size_t ws_size,
                              hipStream_t stream) {
    const float* x  = (const float*)d_in[0];
    const float* W1 = (const float*)d_in[1];
    const float* b1 = (const float*)d_in[2];
    const float* W2 = (const float*)d_in[3];
    const float* b2 = (const float*)d_in[4];
    float* out = (float*)d_out;

    const size_t NX = (size_t)BATCH * TSTEPS * IN_DIM;      // 33.55M elems
    float* cnt_ws = (float*)d_ws;                           // [B, H], 1 MB
    unsigned short* xh = (unsigned short*)((char*)d_ws + (1u << 20));
    unsigned short* xl = xh + NX;
    const size_t need = (1u << 20) + 2 * NX * sizeof(unsigned short);

    if (ws_size >= need) {
        conv_x<<<dim3((unsigned)(NX / (256 * 8))), dim3(256), 0, stream>>>(x, xh, xl);
        snn_mfma_g<<<dim3(256), dim3(256), 0, stream>>>(xh, xl, W1, b1, cnt_ws);
    } else {
        snn_mfma_lds<<<dim3(256), dim3(256), 0, stream>>>(x, W1, b1, cnt_ws);
    }
    snn_out<<<dim3(BATCH), dim3(64), 0, stream>>>(cnt_ws, W2, b2, out);
}

// Round 5
// 274.906 us; speedup vs baseline: 1.7893x; 1.7893x over previous
//
#include <hip/hip_runtime.h>

#define IN_DIM  128
#define HIDDEN  512
#define NCLASS  10
#define TSTEPS  512
#define BATCH   512
#define BETA    0.9f
#define THRESH  0.15f

typedef __attribute__((ext_vector_type(8))) short bf16x8;
typedef __attribute__((ext_vector_type(4))) float f32x4;

__device__ __forceinline__ unsigned short f2bf_rne(float f) {
    unsigned int u = __float_as_uint(f);
    u += 0x7FFFu + ((u >> 16) & 1u);
    return (unsigned short)(u >> 16);
}
__device__ __forceinline__ float bf2f(unsigned short h) {
    return __uint_as_float(((unsigned int)h) << 16);
}

// 8 f32 (scaled by s) -> hi bf16x8 + residual-lo bf16x8 (fp32-accurate split)
__device__ __forceinline__ void cvt8s(const float4 a, const float4 b, float s,
                                      bf16x8* hi, bf16x8* lo) {
    float v[8] = {a.x * s, a.y * s, a.z * s, a.w * s,
                  b.x * s, b.y * s, b.z * s, b.w * s};
#pragma unroll
    for (int e = 0; e < 8; ++e) {
        unsigned short h = f2bf_rne(v[e]);
        (*hi)[e] = (short)h;
        (*lo)[e] = (short)f2bf_rne(v[e] - bf2f(h));
    }
}

// ---------- Pass 1: repack x into MFMA-fragment-ordered bf16 hi/lo tiles ----
// xt layout: tile(bblk,t) = 4096 shorts (8KB): hi[2048] then lo[2048].
// Within hi/lo: group g = kf*64 + l15*4 + lg (g=0..255), 8 elems each:
//   value = 2 * x[bblk*16 + l15][t][kf*32 + lg*8 + e]
// => main-kernel load for (kf): lanes(l15,lg) cover one contiguous 1KB block.
__global__ __launch_bounds__(256, 4) void conv_x2(
    const float* __restrict__ x, unsigned short* __restrict__ xt)
{
    const int bid  = blockIdx.x;          // bblk*512 + t
    const int bblk = bid >> 9;
    const int t    = bid & 511;
    const int g    = threadIdx.x;         // 0..255
    const int kf   = g >> 6;
    const int l15  = (g >> 2) & 15;
    const int lg   = g & 3;

    const float* src = x + ((size_t)(bblk * 16 + l15) * TSTEPS + t) * IN_DIM
                         + kf * 32 + lg * 8;
    const float4* p = reinterpret_cast<const float4*>(src);
    bf16x8 h, l;
    cvt8s(p[0], p[1], 2.0f, &h, &l);

    unsigned short* tile = xt + ((size_t)bblk * TSTEPS + t) * 4096;
    *(bf16x8*)(tile + g * 8)        = h;
    *(bf16x8*)(tile + 2048 + g * 8) = l;
}

// ---------- Pass 2: fused SNN, no LDS, coalesced fragment loads ----------
// Block = 16 batch rows x 64 hidden (4 waves, wave = 16x16 tile). All 4 waves
// read the SAME xt tile (L1 broadcast); W1 hi/lo fragments pinned in VGPRs.
__global__ __launch_bounds__(256, 1) void snn_mfma_g2(
    const unsigned short* __restrict__ xt,  // repacked tiles
    const float* __restrict__ W1,           // [H, 128]
    const float* __restrict__ b1,           // [H]
    float* __restrict__ cnt_ws)             // [B, H]
{
    const int bid  = blockIdx.x;
    const int hblk = bid >> 5;     // 0..7; bid%8 == bblk%8 -> x-sharers co-XCD
    const int bblk = bid & 31;     // 0..31
    const int b0   = bblk * 16;
    const int tid  = threadIdx.x;
    const int wave = tid >> 6;
    const int lane = tid & 63;
    const int l15  = lane & 15;
    const int lg   = lane >> 4;
    const int hbase = hblk * 64 + wave * 16;

    // B-operand fragments from W1 (fp32->hi/lo once; held all T steps)
    bf16x8 whi[4], wlo[4];
    {
        const float* wp = W1 + (size_t)(hbase + l15) * IN_DIM + lg * 8;
#pragma unroll
        for (int kf = 0; kf < 4; ++kf) {
            const float4* p = reinterpret_cast<const float4*>(wp + kf * 32);
            cvt8s(p[0], p[1], 1.0f, &whi[kf], &wlo[kf]);
        }
    }
    const float b1h = b1[hbase + l15];

    // per-lane base into repacked tiles: lane offset = l15*64 + lg*16 bytes
    const char* pb = (const char*)(xt + (size_t)bblk * TSTEPS * 4096)
                   + (l15 * 64 + lg * 16);

    f32x4 mem = {0.f, 0.f, 0.f, 0.f};
    f32x4 cnt = {0.f, 0.f, 0.f, 0.f};

    bf16x8 lxh[4][4], lxl[4][4];   // [slot][kf], static-indexed only
    // prologue: fill slots with t = 0..3
#pragma unroll
    for (int j = 0; j < 4; ++j)
#pragma unroll
        for (int kf = 0; kf < 4; ++kf) {
            lxh[j][kf] = *(const bf16x8*)(pb + j * 8192 + kf * 1024);
            lxl[j][kf] = *(const bf16x8*)(pb + j * 8192 + kf * 1024 + 4096);
        }

#define TSTEP(J, PFJ)                                                          \
    {                                                                          \
        f32x4 chh = {b1h, b1h, b1h, b1h};                                      \
        f32x4 chl = {0.f, 0.f, 0.f, 0.f};                                      \
        f32x4 clh = {0.f, 0.f, 0.f, 0.f};                                      \
        _Pragma("unroll")                                                      \
        for (int kf = 0; kf < 4; ++kf) {                                       \
            chh = __builtin_amdgcn_mfma_f32_16x16x32_bf16(lxh[(J) & 3][kf], whi[kf], chh, 0, 0, 0); \
            chl = __builtin_amdgcn_mfma_f32_16x16x32_bf16(lxh[(J) & 3][kf], wlo[kf], chl, 0, 0, 0); \
            clh = __builtin_amdgcn_mfma_f32_16x16x32_bf16(lxl[(J) & 3][kf], whi[kf], clh, 0, 0, 0); \
        }                                                                      \
        _Pragma("unroll")                                                      \
        for (int kf = 0; kf < 4; ++kf) {                                       \
            lxh[(J) & 3][kf] = *(const bf16x8*)(pb + (PFJ) * 8192 + kf * 1024);        \
            lxl[(J) & 3][kf] = *(const bf16x8*)(pb + (PFJ) * 8192 + kf * 1024 + 4096); \
        }                                                                      \
        _Pragma("unroll")                                                      \
        for (int r = 0; r < 4; ++r) {                                          \
            float cur = (chh[r] + chl[r]) + clh[r];                            \
            float dec = fmaf(BETA, mem[r], cur);                               \
            mem[r] = (mem[r] > THRESH) ? (dec - THRESH) : dec;                 \
            cnt[r] += (mem[r] > THRESH) ? 1.0f : 0.0f;                         \
        }                                                                      \
    }

    for (int w = 0; w < 63; ++w) {
#pragma unroll
        for (int j = 0; j < 8; ++j)
            TSTEP(j, j + 4)
        pb += 8 * 8192;
    }
    // final window: prefetch clamped to t=511 (no OOB, results unused)
#pragma unroll
    for (int j = 0; j < 8; ++j)
        TSTEP(j, 7)
#undef TSTEP

    // store spike counts; C-layout row = lg*4+r, col = l15
    float* cp = cnt_ws + (size_t)b0 * HIDDEN + hbase + l15;
#pragma unroll
    for (int r = 0; r < 4; ++r)
        cp[(size_t)(lg * 4 + r) * HIDDEN] = cnt[r];
}

// ---------- Fallback (R2 path) if ws too small: fused LDS version ----------
__global__ __launch_bounds__(256, 1) void snn_mfma_lds(
    const float* __restrict__ x, const float* __restrict__ W1,
    const float* __restrict__ b1, float* __restrict__ cnt_ws)
{
    __shared__ short ldsA[2][2][16 * IN_DIM];
    const int bid  = blockIdx.x;
    const int hblk = bid >> 5;
    const int bblk = bid & 31;
    const int b0   = bblk * 16;
    const int tid  = threadIdx.x;
    const int wave = tid >> 6;
    const int lane = tid & 63;
    const int l15  = lane & 15;
    const int lg   = lane >> 4;
    const int hbase = hblk * 64 + wave * 16;

    bf16x8 whi[4], wlo[4];
    {
        const float* wp = W1 + (size_t)(hbase + l15) * IN_DIM + lg * 8;
#pragma unroll
        for (int kf = 0; kf < 4; ++kf) {
            const float4* p = reinterpret_cast<const float4*>(wp + kf * 32);
            cvt8s(p[0], p[1], 1.0f, &whi[kf], &wlo[kf]);
        }
    }
    const float b1h = b1[hbase + l15];
    const int m_w  = wave * 4 + lg;
    const int widx = m_w * IN_DIM + ((l15 ^ (m_w & 7)) * 8);
    const float* xrow = x + ((size_t)(b0 + m_w) * TSTEPS) * IN_DIM + l15 * 8;
    int ridx[4];
#pragma unroll
    for (int kf = 0; kf < 4; ++kf)
        ridx[kf] = l15 * IN_DIM + (((lg + 4 * kf) ^ (l15 & 7)) * 8);

    f32x4 mem = {0.f, 0.f, 0.f, 0.f};
    f32x4 cnt = {0.f, 0.f, 0.f, 0.f};
    {
        const float4* p = reinterpret_cast<const float4*>(xrow);
        bf16x8 h8, l8;
        cvt8s(p[0], p[1], 2.0f, &h8, &l8);
        *(bf16x8*)&ldsA[0][0][widx] = h8;
        *(bf16x8*)&ldsA[0][1][widx] = l8;
    }
    float4 rA0, rA1, rB0, rB1;
    {
        const float4* p1 = reinterpret_cast<const float4*>(xrow + 1 * IN_DIM);
        rA0 = p1[0]; rA1 = p1[1];
        const float4* p2 = reinterpret_cast<const float4*>(xrow + 2 * IN_DIM);
        rB0 = p2[0]; rB1 = p2[1];
    }
    __syncthreads();

#define SNN_BODY(T_CUR, RC0, RC1)                                              \
    {                                                                          \
        const int buf = (T_CUR) & 1;                                           \
        if ((T_CUR) + 1 < TSTEPS) {                                            \
            bf16x8 h8, l8;                                                     \
            cvt8s(RC0, RC1, 2.0f, &h8, &l8);                                   \
            *(bf16x8*)&ldsA[buf ^ 1][0][widx] = h8;                            \
            *(bf16x8*)&ldsA[buf ^ 1][1][widx] = l8;                            \
        }                                                                      \
        bf16x8 ahi[4], alo[4];                                                 \
        _Pragma("unroll")                                                      \
        for (int kf = 0; kf < 4; ++kf) {                                       \
            ahi[kf] = *(const bf16x8*)&ldsA[buf][0][ridx[kf]];                 \
            alo[kf] = *(const bf16x8*)&ldsA[buf][1][ridx[kf]];                 \
        }                                                                      \
        {                                                                      \
            int tld = (T_CUR) + 3;                                             \
            if (tld > TSTEPS - 1) tld = TSTEPS - 1;                            \
            const float4* p = reinterpret_cast<const float4*>(                 \
                xrow + (size_t)tld * IN_DIM);                                  \
            RC0 = p[0]; RC1 = p[1];                                            \
        }                                                                      \
        f32x4 chh = {b1h, b1h, b1h, b1h};                                      \
        f32x4 chl = {0.f, 0.f, 0.f, 0.f};                                      \
        f32x4 clh = {0.f, 0.f, 0.f, 0.f};                                      \
        _Pragma("unroll")                                                      \
        for (int kf = 0; kf < 4; ++kf) {                                       \
            chh = __builtin_amdgcn_mfma_f32_16x16x32_bf16(ahi[kf], whi[kf], chh, 0, 0, 0); \
            chl = __builtin_amdgcn_mfma_f32_16x16x32_bf16(ahi[kf], wlo[kf], chl, 0, 0, 0); \
            clh = __builtin_amdgcn_mfma_f32_16x16x32_bf16(alo[kf], whi[kf], clh, 0, 0, 0); \
        }                                                                      \
        _Pragma("unroll")                                                      \
        for (int r = 0; r < 4; ++r) {                                          \
            float cur = (chh[r] + chl[r]) + clh[r];                            \
            float dec = fmaf(BETA, mem[r], cur);                               \
            mem[r] = (mem[r] > THRESH) ? (dec - THRESH) : dec;                 \
            cnt[r] += (mem[r] > THRESH) ? 1.0f : 0.0f;                         \
        }                                                                      \
        __syncthreads();                                                       \
    }

    for (int t = 0; t < TSTEPS; t += 2) {
        SNN_BODY(t,     rA0, rA1)
        SNN_BODY(t + 1, rB0, rB1)
    }
#undef SNN_BODY

    float* cp = cnt_ws + (size_t)b0 * HIDDEN + hbase + l15;
#pragma unroll
    for (int r = 0; r < 4; ++r)
        cp[(size_t)(lg * 4 + r) * HIDDEN] = cnt[r];
}

// out[b,c] = (sum_h cnt[b,h] * W2[c,h]) / T + b2[c]
__global__ __launch_bounds__(64, 1) void snn_out(
    const float* __restrict__ cnt_ws, const float* __restrict__ W2,
    const float* __restrict__ b2, float* __restrict__ out)
{
    const int b = blockIdx.x;
    const int lane = threadIdx.x;
    float c8[8];
#pragma unroll
    for (int j = 0; j < 8; ++j)
        c8[j] = cnt_ws[(size_t)b * HIDDEN + lane + 64 * j];
#pragma unroll
    for (int c = 0; c < NCLASS; ++c) {
        float s = 0.f;
#pragma unroll
        for (int j = 0; j < 8; ++j)
            s = fmaf(c8[j], W2[c * HIDDEN + lane + 64 * j], s);
#pragma unroll
        for (int off = 32; off >= 1; off >>= 1)
            s += __shfl_xor(s, off, 64);
        if (lane == c)
            out[(size_t)b * NCLASS + c] = s * (1.0f / (float)TSTEPS) + b2[c];
    }
}

extern "C" void kernel_launch(void* const* d_in, const int* in_sizes, int n_in,
                              void* d_out, int out_size, void* d_ws, size_t ws_size,
                              hipStream_t stream) {
    const float* x  = (const float*)d_in[0];
    const float* W1 = (const float*)d_in[1];
    const float* b1 = (const float*)d_in[2];
    const float* W2 = (const float*)d_in[3];
    const float* b2 = (const float*)d_in[4];
    float* out = (float*)d_out;

    const size_t NX = (size_t)BATCH * TSTEPS * IN_DIM;      // 33.55M elems
    float* cnt_ws = (float*)d_ws;                           // [B, H], 1 MB
    unsigned short* xt = (unsigned short*)((char*)d_ws + (1u << 20));
    const size_t need = (1u << 20) + 2 * NX * sizeof(unsigned short);

    if (ws_size >= need) {
        conv_x2<<<dim3(32 * TSTEPS), dim3(256), 0, stream>>>(x, xt);
        snn_mfma_g2<<<dim3(256), dim3(256), 0, stream>>>(xt, W1, b1, cnt_ws);
    } else {
        snn_mfma_lds<<<dim3(256), dim3(256), 0, stream>>>(x, W1, b1, cnt_ws);
    }
    snn_out<<<dim3(BATCH), dim3(64), 0, stream>>>(cnt_ws, W2, b2, out);
}

// Round 6
// 179.155 us; speedup vs baseline: 2.7456x; 1.5345x over previous
//
#include <hip/hip_runtime.h>

#define IN_DIM  128
#define HIDDEN  512
#define NCLASS  10
#define TSTEPS  512
#define BATCH   512
#define BETA    0.9f
#define THRESH  0.15f

typedef __attribute__((ext_vector_type(8))) short bf16x8;
typedef __attribute__((ext_vector_type(4))) float f32x4;

__device__ __forceinline__ unsigned short f2bf_rne(float f) {
    unsigned int u = __float_as_uint(f);
    u += 0x7FFFu + ((u >> 16) & 1u);
    return (unsigned short)(u >> 16);
}
__device__ __forceinline__ float bf2f(unsigned short h) {
    return __uint_as_float(((unsigned int)h) << 16);
}

// 8 f32 (scaled by s) -> hi bf16x8 + residual-lo bf16x8 (fp32-accurate split)
__device__ __forceinline__ void cvt8s(const float4 a, const float4 b, float s,
                                      bf16x8* hi, bf16x8* lo) {
    float v[8] = {a.x * s, a.y * s, a.z * s, a.w * s,
                  b.x * s, b.y * s, b.z * s, b.w * s};
#pragma unroll
    for (int e = 0; e < 8; ++e) {
        unsigned short h = f2bf_rne(v[e]);
        (*hi)[e] = (short)h;
        (*lo)[e] = (short)f2bf_rne(v[e] - bf2f(h));
    }
}

// ---------- Pass 1: repack x into MFMA-fragment-ordered bf16 hi/lo tiles ----
// tile(bblk,t) = 8KB: hi[2048 shorts] then lo[2048 shorts].
// group g = kf*64 + l15*4 + lg, 8 elems: 2*x[bblk*16+l15][t][kf*32+lg*8+e]
__global__ __launch_bounds__(256, 4) void conv_x2(
    const float* __restrict__ x, unsigned short* __restrict__ xt)
{
    const int bid  = blockIdx.x;          // bblk*512 + t
    const int bblk = bid >> 9;
    const int t    = bid & 511;
    const int g    = threadIdx.x;         // 0..255
    const int kf   = g >> 6;
    const int l15  = (g >> 2) & 15;
    const int lg   = g & 3;

    const float* src = x + ((size_t)(bblk * 16 + l15) * TSTEPS + t) * IN_DIM
                         + kf * 32 + lg * 8;
    const float4* p = reinterpret_cast<const float4*>(src);
    bf16x8 h, l;
    cvt8s(p[0], p[1], 2.0f, &h, &l);

    unsigned short* tile = xt + ((size_t)bblk * TSTEPS + t) * 4096;
    *(bf16x8*)(tile + g * 8)        = h;
    *(bf16x8*)(tile + 2048 + g * 8) = l;
}

// ---------- Pass 2: fused SNN with async LDS ring pipeline ----------
// Block = 16 batch rows x 64 hidden (4 waves). 8-slot LDS ring of 8KB tiles,
// global_load_lds staging, counted vmcnt(12) (7 tiles in flight), one raw
// s_barrier per t. Fragment ds_reads are contiguous 1KB/wave -> conflict-free.
__global__ __launch_bounds__(256, 1) void snn_mfma_l(
    const unsigned short* __restrict__ xt,
    const float* __restrict__ W1, const float* __restrict__ b1,
    float* __restrict__ cnt_ws)
{
    __shared__ char ring[8][8192];   // 64 KB

    const int bid  = blockIdx.x;
    const int hblk = bid >> 5;     // bid%8 == bblk%8 -> x-sharers co-XCD
    const int bblk = bid & 31;
    const int b0   = bblk * 16;
    const int tid  = threadIdx.x;
    const int wave = tid >> 6;
    const int lane = tid & 63;
    const int l15  = lane & 15;
    const int lg   = lane >> 4;
    const int hbase = hblk * 64 + wave * 16;

    // B-operand fragments from W1 (fp32->hi/lo once; held all T steps)
    bf16x8 whi[4], wlo[4];
    {
        const float* wp = W1 + (size_t)(hbase + l15) * IN_DIM + lg * 8;
#pragma unroll
        for (int kf = 0; kf < 4; ++kf) {
            const float4* p = reinterpret_cast<const float4*>(wp + kf * 32);
            cvt8s(p[0], p[1], 1.0f, &whi[kf], &wlo[kf]);
        }
    }
    const float b1h = b1[hbase + l15];

    const char* gb = (const char*)xt + (size_t)bblk * TSTEPS * 8192;
    char* lbase = &ring[0][0];
    const int woff   = wave * 1024;          // wave-uniform LDS offset
    const int lane16 = lane * 16;

    f32x4 mem = {0.f, 0.f, 0.f, 0.f};
    f32x4 cnt = {0.f, 0.f, 0.f, 0.f};

#define STAGE(TT, SLOT)                                                        \
    {                                                                          \
        const char* g_ = gb + (size_t)(TT) * 8192 + woff + lane16;             \
        char* l_ = lbase + (SLOT) * 8192 + woff;                               \
        __builtin_amdgcn_global_load_lds(                                      \
            (const __attribute__((address_space(1))) void*)g_,                 \
            (__attribute__((address_space(3))) void*)l_, 16, 0, 0);            \
        __builtin_amdgcn_global_load_lds(                                      \
            (const __attribute__((address_space(1))) void*)(g_ + 4096),        \
            (__attribute__((address_space(3))) void*)(l_ + 4096), 16, 0, 0);   \
    }

    // prologue: drain W1 loads, then issue tiles 0..6 (14 loads in flight)
    asm volatile("s_waitcnt vmcnt(0)" ::: "memory");
#pragma unroll
    for (int j = 0; j < 7; ++j)
        STAGE(j, j)

    for (int w = 0; w < 64; ++w) {
#pragma unroll
        for (int j = 0; j < 8; ++j) {
            const int t = w * 8 + j;
            // my tile-t loads landed (<=12 outstanding = tiles t+1..t+6)
            asm volatile("s_waitcnt vmcnt(12)" ::: "memory");
            __builtin_amdgcn_s_barrier();     // everyone's tile-t landed;
            asm volatile("" ::: "memory");    // no LDS-read hoist above this
            // issue tile t+7 into slot (t-1)&7 (consumed at t-1, all done)
            {
                int tt = t + 7; if (tt > TSTEPS - 1) tt = TSTEPS - 1;
                STAGE(tt, (j + 7) & 7)
            }
            // fragments from slot j (contiguous 1KB per kf -> conflict-free)
            const short* tp = (const short*)&ring[j][0];
            bf16x8 ahi[4], alo[4];
#pragma unroll
            for (int kf = 0; kf < 4; ++kf) {
                ahi[kf] = *(const bf16x8*)(tp + kf * 512 + l15 * 32 + lg * 8);
                alo[kf] = *(const bf16x8*)(tp + 2048 + kf * 512 + l15 * 32 + lg * 8);
            }
            f32x4 chh = {b1h, b1h, b1h, b1h};
            f32x4 chl = {0.f, 0.f, 0.f, 0.f};
            f32x4 clh = {0.f, 0.f, 0.f, 0.f};
#pragma unroll
            for (int kf = 0; kf < 4; ++kf) {
                chh = __builtin_amdgcn_mfma_f32_16x16x32_bf16(ahi[kf], whi[kf], chh, 0, 0, 0);
                chl = __builtin_amdgcn_mfma_f32_16x16x32_bf16(ahi[kf], wlo[kf], chl, 0, 0, 0);
                clh = __builtin_amdgcn_mfma_f32_16x16x32_bf16(alo[kf], whi[kf], clh, 0, 0, 0);
            }
#pragma unroll
            for (int r = 0; r < 4; ++r) {
                float cur = (chh[r] + chl[r]) + clh[r];
                float dec = fmaf(BETA, mem[r], cur);
                mem[r] = (mem[r] > THRESH) ? (dec - THRESH) : dec;
                cnt[r] += (mem[r] > THRESH) ? 1.0f : 0.0f;
            }
        }
    }
#undef STAGE

    // store spike counts; C-layout row = lg*4+r, col = l15
    float* cp = cnt_ws + (size_t)b0 * HIDDEN + hbase + l15;
#pragma unroll
    for (int r = 0; r < 4; ++r)
        cp[(size_t)(lg * 4 + r) * HIDDEN] = cnt[r];
}

// ---------- Fallback (proven R2 path) if ws too small ----------
__global__ __launch_bounds__(256, 1) void snn_mfma_lds(
    const float* __restrict__ x, const float* __restrict__ W1,
    const float* __restrict__ b1, float* __restrict__ cnt_ws)
{
    __shared__ short ldsA[2][2][16 * IN_DIM];
    const int bid  = blockIdx.x;
    const int hblk = bid >> 5;
    const int bblk = bid & 31;
    const int b0   = bblk * 16;
    const int tid  = threadIdx.x;
    const int wave = tid >> 6;
    const int lane = tid & 63;
    const int l15  = lane & 15;
    const int lg   = lane >> 4;
    const int hbase = hblk * 64 + wave * 16;

    bf16x8 whi[4], wlo[4];
    {
        const float* wp = W1 + (size_t)(hbase + l15) * IN_DIM + lg * 8;
#pragma unroll
        for (int kf = 0; kf < 4; ++kf) {
            const float4* p = reinterpret_cast<const float4*>(wp + kf * 32);
            cvt8s(p[0], p[1], 1.0f, &whi[kf], &wlo[kf]);
        }
    }
    const float b1h = b1[hbase + l15];
    const int m_w  = wave * 4 + lg;
    const int widx = m_w * IN_DIM + ((l15 ^ (m_w & 7)) * 8);
    const float* xrow = x + ((size_t)(b0 + m_w) * TSTEPS) * IN_DIM + l15 * 8;
    int ridx[4];
#pragma unroll
    for (int kf = 0; kf < 4; ++kf)
        ridx[kf] = l15 * IN_DIM + (((lg + 4 * kf) ^ (l15 & 7)) * 8);

    f32x4 mem = {0.f, 0.f, 0.f, 0.f};
    f32x4 cnt = {0.f, 0.f, 0.f, 0.f};
    {
        const float4* p = reinterpret_cast<const float4*>(xrow);
        bf16x8 h8, l8;
        cvt8s(p[0], p[1], 2.0f, &h8, &l8);
        *(bf16x8*)&ldsA[0][0][widx] = h8;
        *(bf16x8*)&ldsA[0][1][widx] = l8;
    }
    float4 rA0, rA1, rB0, rB1;
    {
        const float4* p1 = reinterpret_cast<const float4*>(xrow + 1 * IN_DIM);
        rA0 = p1[0]; rA1 = p1[1];
        const float4* p2 = reinterpret_cast<const float4*>(xrow + 2 * IN_DIM);
        rB0 = p2[0]; rB1 = p2[1];
    }
    __syncthreads();

#define SNN_BODY(T_CUR, RC0, RC1)                                              \
    {                                                                          \
        const int buf = (T_CUR) & 1;                                           \
        if ((T_CUR) + 1 < TSTEPS) {                                            \
            bf16x8 h8, l8;                                                     \
            cvt8s(RC0, RC1, 2.0f, &h8, &l8);                                   \
            *(bf16x8*)&ldsA[buf ^ 1][0][widx] = h8;                            \
            *(bf16x8*)&ldsA[buf ^ 1][1][widx] = l8;                            \
        }                                                                      \
        bf16x8 ahi[4], alo[4];                                                 \
        _Pragma("unroll")                                                      \
        for (int kf = 0; kf < 4; ++kf) {                                       \
            ahi[kf] = *(const bf16x8*)&ldsA[buf][0][ridx[kf]];                 \
            alo[kf] = *(const bf16x8*)&ldsA[buf][1][ridx[kf]];                 \
        }                                                                      \
        {                                                                      \
            int tld = (T_CUR) + 3;                                             \
            if (tld > TSTEPS - 1) tld = TSTEPS - 1;                            \
            const float4* p = reinterpret_cast<const float4*>(                 \
                xrow + (size_t)tld * IN_DIM);                                  \
            RC0 = p[0]; RC1 = p[1];                                            \
        }                                                                      \
        f32x4 chh = {b1h, b1h, b1h, b1h};                                      \
        f32x4 chl = {0.f, 0.f, 0.f, 0.f};                                      \
        f32x4 clh = {0.f, 0.f, 0.f, 0.f};                                      \
        _Pragma("unroll")                                                      \
        for (int kf = 0; kf < 4; ++kf) {                                       \
            chh = __builtin_amdgcn_mfma_f32_16x16x32_bf16(ahi[kf], whi[kf], chh, 0, 0, 0); \
            chl = __builtin_amdgcn_mfma_f32_16x16x32_bf16(ahi[kf], wlo[kf], chl, 0, 0, 0); \
            clh = __builtin_amdgcn_mfma_f32_16x16x32_bf16(alo[kf], whi[kf], clh, 0, 0, 0); \
        }                                                                      \
        _Pragma("unroll")                                                      \
        for (int r = 0; r < 4; ++r) {                                          \
            float cur = (chh[r] + chl[r]) + clh[r];                            \
            float dec = fmaf(BETA, mem[r], cur);                               \
            mem[r] = (mem[r] > THRESH) ? (dec - THRESH) : dec;                 \
            cnt[r] += (mem[r] > THRESH) ? 1.0f : 0.0f;                         \
        }                                                                      \
        __syncthreads();                                                       \
    }

    for (int t = 0; t < TSTEPS; t += 2) {
        SNN_BODY(t,     rA0, rA1)
        SNN_BODY(t + 1, rB0, rB1)
    }
#undef SNN_BODY

    float* cp = cnt_ws + (size_t)b0 * HIDDEN + hbase + l15;
#pragma unroll
    for (int r = 0; r < 4; ++r)
        cp[(size_t)(lg * 4 + r) * HIDDEN] = cnt[r];
}

// out[b,c] = (sum_h cnt[b,h] * W2[c,h]) / T + b2[c]
__global__ __launch_bounds__(64, 1) void snn_out(
    const float* __restrict__ cnt_ws, const float* __restrict__ W2,
    const float* __restrict__ b2, float* __restrict__ out)
{
    const int b = blockIdx.x;
    const int lane = threadIdx.x;
    float c8[8];
#pragma unroll
    for (int j = 0; j < 8; ++j)
        c8[j] = cnt_ws[(size_t)b * HIDDEN + lane + 64 * j];
#pragma unroll
    for (int c = 0; c < NCLASS; ++c) {
        float s = 0.f;
#pragma unroll
        for (int j = 0; j < 8; ++j)
            s = fmaf(c8[j], W2[c * HIDDEN + lane + 64 * j], s);
#pragma unroll
        for (int off = 32; off >= 1; off >>= 1)
            s += __shfl_xor(s, off, 64);
        if (lane == c)
            out[(size_t)b * NCLASS + c] = s * (1.0f / (float)TSTEPS) + b2[c];
    }
}

extern "C" void kernel_launch(void* const* d_in, const int* in_sizes, int n_in,
                              void* d_out, int out_size, void* d_ws, size_t ws_size,
                              hipStream_t stream) {
    const float* x  = (const float*)d_in[0];
    const float* W1 = (const float*)d_in[1];
    const float* b1 = (const float*)d_in[2];
    const float* W2 = (const float*)d_in[3];
    const float* b2 = (const float*)d_in[4];
    float* out = (float*)d_out;

    const size_t NX = (size_t)BATCH * TSTEPS * IN_DIM;      // 33.55M elems
    float* cnt_ws = (float*)d_ws;                           // [B, H], 1 MB
    unsigned short* xt = (unsigned short*)((char*)d_ws + (1u << 20));
    const size_t need = (1u << 20) + 2 * NX * sizeof(unsigned short);

    if (ws_size >= need) {
        conv_x2<<<dim3(32 * TSTEPS), dim3(256), 0, stream>>>(x, xt);
        snn_mfma_l<<<dim3(256), dim3(256), 0, stream>>>(xt, W1, b1, cnt_ws);
    } else {
        snn_mfma_lds<<<dim3(256), dim3(256), 0, stream>>>(x, W1, b1, cnt_ws);
    }
    snn_out<<<dim3(BATCH), dim3(64), 0, stream>>>(cnt_ws, W2, b2, out);
}

// Round 7
// 166.701 us; speedup vs baseline: 2.9508x; 1.0747x over previous
//
#include <hip/hip_runtime.h>

#define IN_DIM  128
#define HIDDEN  512
#define NCLASS  10
#define TSTEPS  512
#define BATCH   512
#define BETA    0.9f
#define THRESH  0.15f

typedef __attribute__((ext_vector_type(8))) short bf16x8;
typedef __attribute__((ext_vector_type(4))) float f32x4;

__device__ __forceinline__ unsigned short f2bf_rne(float f) {
    unsigned int u = __float_as_uint(f);
    u += 0x7FFFu + ((u >> 16) & 1u);
    return (unsigned short)(u >> 16);
}
__device__ __forceinline__ float bf2f(unsigned short h) {
    return __uint_as_float(((unsigned int)h) << 16);
}

// 8 f32 (scaled by s) -> hi bf16x8 + residual-lo bf16x8 (fp32-accurate split)
__device__ __forceinline__ void cvt8s(const float4 a, const float4 b, float s,
                                      bf16x8* hi, bf16x8* lo) {
    float v[8] = {a.x * s, a.y * s, a.z * s, a.w * s,
                  b.x * s, b.y * s, b.z * s, b.w * s};
#pragma unroll
    for (int e = 0; e < 8; ++e) {
        unsigned short h = f2bf_rne(v[e]);
        (*hi)[e] = (short)h;
        (*lo)[e] = (short)f2bf_rne(v[e] - bf2f(h));
    }
}

// ---------- Pass 1: repack x into LANE-LINEAR MFMA fragment tiles ----------
// tile(bblk,t) = 8KB: hi[2048 shorts] then lo[2048 shorts].
// Fragment element for wave-lane i (row=i&15, k-sub=i>>4), k-chunk kf lives at
// short index kf*512 + i*8  => each wave ds_read_b128 is 1KB contiguous,
// bank-conflict-free. Thread g: kf=g>>6, i=g&63 (l15=i&15, lg=i>>4).
__global__ __launch_bounds__(256, 4) void conv_x2(
    const float* __restrict__ x, unsigned short* __restrict__ xt)
{
    const int bid  = blockIdx.x;          // bblk*512 + t
    const int bblk = bid >> 9;
    const int t    = bid & 511;
    const int g    = threadIdx.x;         // 0..255
    const int kf   = g >> 6;
    const int i    = g & 63;
    const int l15  = i & 15;
    const int lg   = i >> 4;

    const float* src = x + ((size_t)(bblk * 16 + l15) * TSTEPS + t) * IN_DIM
                         + kf * 32 + lg * 8;
    const float4* p = reinterpret_cast<const float4*>(src);
    bf16x8 h, l;
    cvt8s(p[0], p[1], 2.0f, &h, &l);

    unsigned short* tile = xt + ((size_t)bblk * TSTEPS + t) * 4096;
    *(bf16x8*)(tile + g * 8)        = h;   // g*8 == kf*512 + i*8
    *(bf16x8*)(tile + 2048 + g * 8) = l;
}

// ---------- Pass 2: fused SNN with async LDS ring pipeline ----------
// Block = 16 batch rows x 64 hidden (4 waves). 8-slot LDS ring of 8KB tiles,
// global_load_lds staging, counted vmcnt(12) (tiles stay in flight), one raw
// s_barrier per t. Fragment ds_reads now lane-linear -> conflict-free.
__global__ __launch_bounds__(256, 1) void snn_mfma_l(
    const unsigned short* __restrict__ xt,
    const float* __restrict__ W1, const float* __restrict__ b1,
    float* __restrict__ cnt_ws)
{
    __shared__ char ring[8][8192];   // 64 KB

    const int bid  = blockIdx.x;
    const int hblk = bid >> 5;     // bid%8 == bblk%8 -> x-sharers co-XCD
    const int bblk = bid & 31;
    const int b0   = bblk * 16;
    const int tid  = threadIdx.x;
    const int wave = tid >> 6;
    const int lane = tid & 63;
    const int l15  = lane & 15;
    const int lg   = lane >> 4;
    const int hbase = hblk * 64 + wave * 16;

    // B-operand fragments from W1 (fp32->hi/lo once; held all T steps)
    bf16x8 whi[4], wlo[4];
    {
        const float* wp = W1 + (size_t)(hbase + l15) * IN_DIM + lg * 8;
#pragma unroll
        for (int kf = 0; kf < 4; ++kf) {
            const float4* p = reinterpret_cast<const float4*>(wp + kf * 32);
            cvt8s(p[0], p[1], 1.0f, &whi[kf], &wlo[kf]);
        }
    }
    const float b1h = b1[hbase + l15];

    const char* gb = (const char*)xt + (size_t)bblk * TSTEPS * 8192;
    char* lbase = &ring[0][0];
    const int woff   = wave * 1024;          // wave-uniform LDS offset
    const int lane16 = lane * 16;

    f32x4 mem = {0.f, 0.f, 0.f, 0.f};
    f32x4 cnt = {0.f, 0.f, 0.f, 0.f};

#define STAGE(TT, SLOT)                                                        \
    {                                                                          \
        const char* g_ = gb + (size_t)(TT) * 8192 + woff + lane16;             \
        char* l_ = lbase + (SLOT) * 8192 + woff;                               \
        __builtin_amdgcn_global_load_lds(                                      \
            (const __attribute__((address_space(1))) void*)g_,                 \
            (__attribute__((address_space(3))) void*)l_, 16, 0, 0);            \
        __builtin_amdgcn_global_load_lds(                                      \
            (const __attribute__((address_space(1))) void*)(g_ + 4096),        \
            (__attribute__((address_space(3))) void*)(l_ + 4096), 16, 0, 0);   \
    }

    // prologue: drain W1 loads, then issue tiles 0..6 (14 loads in flight)
    asm volatile("s_waitcnt vmcnt(0)" ::: "memory");
#pragma unroll
    for (int j = 0; j < 7; ++j)
        STAGE(j, j)

    for (int w = 0; w < 64; ++w) {
#pragma unroll
        for (int j = 0; j < 8; ++j) {
            const int t = w * 8 + j;
            // my tile-t loads landed (<=12 outstanding = tiles t+1..t+6)
            asm volatile("s_waitcnt vmcnt(12)" ::: "memory");
            __builtin_amdgcn_s_barrier();     // everyone's tile-t landed
            asm volatile("" ::: "memory");    // no LDS-read hoist above this
            // issue tile t+7 into slot (t-1)&7 (consumed at t-1, all done)
            {
                int tt = t + 7; if (tt > TSTEPS - 1) tt = TSTEPS - 1;
                STAGE(tt, (j + 7) & 7)
            }
            // fragments from slot j: lane-linear 1KB per kf -> conflict-free
            const short* tp = (const short*)&ring[j][0];
            bf16x8 ahi[4], alo[4];
#pragma unroll
            for (int kf = 0; kf < 4; ++kf) {
                ahi[kf] = *(const bf16x8*)(tp + kf * 512 + lane * 8);
                alo[kf] = *(const bf16x8*)(tp + 2048 + kf * 512 + lane * 8);
            }
            f32x4 chh = {b1h, b1h, b1h, b1h};
            f32x4 chl = {0.f, 0.f, 0.f, 0.f};
            f32x4 clh = {0.f, 0.f, 0.f, 0.f};
#pragma unroll
            for (int kf = 0; kf < 4; ++kf) {
                chh = __builtin_amdgcn_mfma_f32_16x16x32_bf16(ahi[kf], whi[kf], chh, 0, 0, 0);
                chl = __builtin_amdgcn_mfma_f32_16x16x32_bf16(ahi[kf], wlo[kf], chl, 0, 0, 0);
                clh = __builtin_amdgcn_mfma_f32_16x16x32_bf16(alo[kf], whi[kf], clh, 0, 0, 0);
            }
#pragma unroll
            for (int r = 0; r < 4; ++r) {
                float cur = (chh[r] + chl[r]) + clh[r];
                float dec = fmaf(BETA, mem[r], cur);
                mem[r] = (mem[r] > THRESH) ? (dec - THRESH) : dec;
                cnt[r] += (mem[r] > THRESH) ? 1.0f : 0.0f;
            }
        }
    }
#undef STAGE

    // store spike counts; C-layout row = lg*4+r, col = l15
    float* cp = cnt_ws + (size_t)b0 * HIDDEN + hbase + l15;
#pragma unroll
    for (int r = 0; r < 4; ++r)
        cp[(size_t)(lg * 4 + r) * HIDDEN] = cnt[r];
}

// ---------- Fallback (proven R2 path) if ws too small ----------
__global__ __launch_bounds__(256, 1) void snn_mfma_lds(
    const float* __restrict__ x, const float* __restrict__ W1,
    const float* __restrict__ b1, float* __restrict__ cnt_ws)
{
    __shared__ short ldsA[2][2][16 * IN_DIM];
    const int bid  = blockIdx.x;
    const int hblk = bid >> 5;
    const int bblk = bid & 31;
    const int b0   = bblk * 16;
    const int tid  = threadIdx.x;
    const int wave = tid >> 6;
    const int lane = tid & 63;
    const int l15  = lane & 15;
    const int lg   = lane >> 4;
    const int hbase = hblk * 64 + wave * 16;

    bf16x8 whi[4], wlo[4];
    {
        const float* wp = W1 + (size_t)(hbase + l15) * IN_DIM + lg * 8;
#pragma unroll
        for (int kf = 0; kf < 4; ++kf) {
            const float4* p = reinterpret_cast<const float4*>(wp + kf * 32);
            cvt8s(p[0], p[1], 1.0f, &whi[kf], &wlo[kf]);
        }
    }
    const float b1h = b1[hbase + l15];
    const int m_w  = wave * 4 + lg;
    const int widx = m_w * IN_DIM + ((l15 ^ (m_w & 7)) * 8);
    const float* xrow = x + ((size_t)(b0 + m_w) * TSTEPS) * IN_DIM + l15 * 8;
    int ridx[4];
#pragma unroll
    for (int kf = 0; kf < 4; ++kf)
        ridx[kf] = l15 * IN_DIM + (((lg + 4 * kf) ^ (l15 & 7)) * 8);

    f32x4 mem = {0.f, 0.f, 0.f, 0.f};
    f32x4 cnt = {0.f, 0.f, 0.f, 0.f};
    {
        const float4* p = reinterpret_cast<const float4*>(xrow);
        bf16x8 h8, l8;
        cvt8s(p[0], p[1], 2.0f, &h8, &l8);
        *(bf16x8*)&ldsA[0][0][widx] = h8;
        *(bf16x8*)&ldsA[0][1][widx] = l8;
    }
    float4 rA0, rA1, rB0, rB1;
    {
        const float4* p1 = reinterpret_cast<const float4*>(xrow + 1 * IN_DIM);
        rA0 = p1[0]; rA1 = p1[1];
        const float4* p2 = reinterpret_cast<const float4*>(xrow + 2 * IN_DIM);
        rB0 = p2[0]; rB1 = p2[1];
    }
    __syncthreads();

#define SNN_BODY(T_CUR, RC0, RC1)                                              \
    {                                                                          \
        const int buf = (T_CUR) & 1;                                           \
        if ((T_CUR) + 1 < TSTEPS) {                                            \
            bf16x8 h8, l8;                                                     \
            cvt8s(RC0, RC1, 2.0f, &h8, &l8);                                   \
            *(bf16x8*)&ldsA[buf ^ 1][0][widx] = h8;                            \
            *(bf16x8*)&ldsA[buf ^ 1][1][widx] = l8;                            \
        }                                                                      \
        bf16x8 ahi[4], alo[4];                                                 \
        _Pragma("unroll")                                                      \
        for (int kf = 0; kf < 4; ++kf) {                                       \
            ahi[kf] = *(const bf16x8*)&ldsA[buf][0][ridx[kf]];                 \
            alo[kf] = *(const bf16x8*)&ldsA[buf][1][ridx[kf]];                 \
        }                                                                      \
        {                                                                      \
            int tld = (T_CUR) + 3;                                             \
            if (tld > TSTEPS - 1) tld = TSTEPS - 1;                            \
            const float4* p = reinterpret_cast<const float4*>(                 \
                xrow + (size_t)tld * IN_DIM);                                  \
            RC0 = p[0]; RC1 = p[1];                                            \
        }                                                                      \
        f32x4 chh = {b1h, b1h, b1h, b1h};                                      \
        f32x4 chl = {0.f, 0.f, 0.f, 0.f};                                      \
        f32x4 clh = {0.f, 0.f, 0.f, 0.f};                                      \
        _Pragma("unroll")                                                      \
        for (int kf = 0; kf < 4; ++kf) {                                       \
            chh = __builtin_amdgcn_mfma_f32_16x16x32_bf16(ahi[kf], whi[kf], chh, 0, 0, 0); \
            chl = __builtin_amdgcn_mfma_f32_16x16x32_bf16(ahi[kf], wlo[kf], chl, 0, 0, 0); \
            clh = __builtin_amdgcn_mfma_f32_16x16x32_bf16(alo[kf], whi[kf], clh, 0, 0, 0); \
        }                                                                      \
        _Pragma("unroll")                                                      \
        for (int r = 0; r < 4; ++r) {                                          \
            float cur = (chh[r] + chl[r]) + clh[r];                            \
            float dec = fmaf(BETA, mem[r], cur);                               \
            mem[r] = (mem[r] > THRESH) ? (dec - THRESH) : dec;                 \
            cnt[r] += (mem[r] > THRESH) ? 1.0f : 0.0f;                         \
        }                                                                      \
        __syncthreads();                                                       \
    }

    for (int t = 0; t < TSTEPS; t += 2) {
        SNN_BODY(t,     rA0, rA1)
        SNN_BODY(t + 1, rB0, rB1)
    }
#undef SNN_BODY

    float* cp = cnt_ws + (size_t)b0 * HIDDEN + hbase + l15;
#pragma unroll
    for (int r = 0; r < 4; ++r)
        cp[(size_t)(lg * 4 + r) * HIDDEN] = cnt[r];
}

// out[b,c] = (sum_h cnt[b,h] * W2[c,h]) / T + b2[c]
__global__ __launch_bounds__(64, 1) void snn_out(
    const float* __restrict__ cnt_ws, const float* __restrict__ W2,
    const float* __restrict__ b2, float* __restrict__ out)
{
    const int b = blockIdx.x;
    const int lane = threadIdx.x;
    float c8[8];
#pragma unroll
    for (int j = 0; j < 8; ++j)
        c8[j] = cnt_ws[(size_t)b * HIDDEN + lane + 64 * j];
#pragma unroll
    for (int c = 0; c < NCLASS; ++c) {
        float s = 0.f;
#pragma unroll
        for (int j = 0; j < 8; ++j)
            s = fmaf(c8[j], W2[c * HIDDEN + lane + 64 * j], s);
#pragma unroll
        for (int off = 32; off >= 1; off >>= 1)
            s += __shfl_xor(s, off, 64);
        if (lane == c)
            out[(size_t)b * NCLASS + c] = s * (1.0f / (float)TSTEPS) + b2[c];
    }
}

extern "C" void kernel_launch(void* const* d_in, const int* in_sizes, int n_in,
                              void* d_out, int out_size, void* d_ws, size_t ws_size,
                              hipStream_t stream) {
    const float* x  = (const float*)d_in[0];
    const float* W1 = (const float*)d_in[1];
    const float* b1 = (const float*)d_in[2];
    const float* W2 = (const float*)d_in[3];
    const float* b2 = (const float*)d_in[4];
    float* out = (float*)d_out;

    const size_t NX = (size_t)BATCH * TSTEPS * IN_DIM;      // 33.55M elems
    float* cnt_ws = (float*)d_ws;                           // [B, H], 1 MB
    unsigned short* xt = (unsigned short*)((char*)d_ws + (1u << 20));
    const size_t need = (1u << 20) + 2 * NX * sizeof(unsigned short);

    if (ws_size >= need) {
        conv_x2<<<dim3(32 * TSTEPS), dim3(256), 0, stream>>>(x, xt);
        snn_mfma_l<<<dim3(256), dim3(256), 0, stream>>>(xt, W1, b1, cnt_ws);
    } else {
        snn_mfma_lds<<<dim3(256), dim3(256), 0, stream>>>(x, W1, b1, cnt_ws);
    }
    snn_out<<<dim3(BATCH), dim3(64), 0, stream>>>(cnt_ws, W2, b2, out);
}